// Round 1
// baseline (159.699 us; speedup 1.0000x reference)
//
#include <hip/hip_runtime.h>
#include <hip/hip_bf16.h>

#define NHEAD 12
#define HSZ   64
#define BATCH 8
#define SEQ   1024
#define KDIM  768
#define NDIM  1536   // NHEAD * HSZ * 2

using f32x4  = __attribute__((ext_vector_type(4))) float;
using bf16x8 = __attribute__((ext_vector_type(8))) __bf16;

__device__ __forceinline__ unsigned short f2bf(float f) {
    unsigned int u = __builtin_bit_cast(unsigned int, f);
    u += 0x7fffu + ((u >> 16) & 1u);   // RNE
    return (unsigned short)(u >> 16);
}

// sin/cos table: tab[s*32 + i] = (sin(s*invfreq_i), cos(s*invfreq_i))
__global__ void fill_table(float2* __restrict__ tab) {
    int idx = blockIdx.x * 256 + threadIdx.x;
    if (idx >= SEQ * 32) return;
    int s = idx >> 5, i = idx & 31;
    // invfreq_i = 10000^(-i/32) = exp2(-i * log2(10000)/32)
    float inv = exp2f(-(float)i * (13.287712379549449f / 32.0f));
    float ang = (float)s * inv;
    tab[idx] = make_float2(sinf(ang), cosf(ang));
}

// Wt[n][k] = bf16(W[k][n]);  W is [768][1536] fp32 row-major
__global__ void transpose_w(const float* __restrict__ W, unsigned short* __restrict__ Wt) {
    __shared__ unsigned short tl[32][33];
    int n0 = blockIdx.x * 32, k0 = blockIdx.y * 32;
    int tx = threadIdx.x & 31, ty = threadIdx.x >> 5;   // 32 x 8
#pragma unroll
    for (int r = 0; r < 4; ++r)
        tl[ty + r * 8][tx] = f2bf(W[(size_t)(k0 + ty + r * 8) * NDIM + n0 + tx]);
    __syncthreads();
#pragma unroll
    for (int r = 0; r < 4; ++r)
        Wt[(size_t)(n0 + ty + r * 8) * KDIM + k0 + tx] = tl[tx][ty + r * 8];
}

// byte offset within a 128B LDS row, XOR-swizzled on 16B blocks
__device__ __forceinline__ int swz16(int row, int c16) { return (c16 ^ (row & 7)); }

// GEMM1: hidden = input @ W + b, then RoPE, write Q/K bf16 to ws.
// Tile 128(M) x 128(N), BK=64, 4 waves (2x2), each wave 64x64.
// N-tile == one head (128 cols); wave n-half 0 -> q, 1 -> k.
__global__ __launch_bounds__(256) void gemm1_rope(
        const float* __restrict__ input, const unsigned short* __restrict__ Wt,
        const float* __restrict__ bias, const float2* __restrict__ tab,
        unsigned short* __restrict__ qws, unsigned short* __restrict__ kws) {
    __shared__ unsigned short As[128 * 64];   // [m][k] bf16, swizzled
    __shared__ unsigned short Bs[128 * 64];   // [n][k] bf16, swizzled
    const int t  = threadIdx.x;
    const int nt = blockIdx.x, mt = blockIdx.y;
    const int m0 = mt * 128, n0 = nt * 128;
    const int lane = t & 63, wid = t >> 6;
    const int wm = wid >> 1, wn = wid & 1;
    const int lr = lane & 15, lg = lane >> 4;

    f32x4 acc[4][4] = {};

    char* asb = reinterpret_cast<char*>(As);
    char* bsb = reinterpret_cast<char*>(Bs);

    for (int kt = 0; kt < KDIM / 64; ++kt) {
        if (kt) __syncthreads();
        const int kbase = kt * 64;
        {   // stage A: 128 rows x 64 k, fp32 -> bf16.  slot = float4 of k.
            const int slot = t & 15, r0 = t >> 4;
#pragma unroll
            for (int ii = 0; ii < 8; ++ii) {
                const int r = r0 + ii * 16;
                const f32x4 v = *reinterpret_cast<const f32x4*>(
                    &input[(size_t)(m0 + r) * KDIM + kbase + slot * 4]);
                unsigned int p0 = (unsigned int)f2bf(v[0]) | ((unsigned int)f2bf(v[1]) << 16);
                unsigned int p1 = (unsigned int)f2bf(v[2]) | ((unsigned int)f2bf(v[3]) << 16);
                const int byte = r * 128 + swz16(r, slot >> 1) * 16 + (slot & 1) * 8;
                *reinterpret_cast<uint2*>(asb + byte) = make_uint2(p0, p1);
            }
        }
        {   // stage B from Wt: 128 rows(n) x 64 k bf16, 16B per thread-slot
            const int c16 = t & 7, r0 = t >> 3;
#pragma unroll
            for (int ii = 0; ii < 4; ++ii) {
                const int r = r0 + ii * 32;
                const uint4 v = *reinterpret_cast<const uint4*>(
                    &Wt[(size_t)(n0 + r) * KDIM + kbase + c16 * 8]);
                const int byte = r * 128 + swz16(r, c16) * 16;
                *reinterpret_cast<uint4*>(bsb + byte) = v;
            }
        }
        __syncthreads();
#pragma unroll
        for (int kk = 0; kk < 2; ++kk) {
            bf16x8 a[4], b[4];
#pragma unroll
            for (int mf = 0; mf < 4; ++mf) {
                const int r = wm * 64 + mf * 16 + lr;
                a[mf] = *reinterpret_cast<const bf16x8*>(asb + r * 128 + swz16(r, kk * 4 + lg) * 16);
            }
#pragma unroll
            for (int nf = 0; nf < 4; ++nf) {
                const int r = wn * 64 + nf * 16 + lr;
                b[nf] = *reinterpret_cast<const bf16x8*>(bsb + r * 128 + swz16(r, kk * 4 + lg) * 16);
            }
#pragma unroll
            for (int mf = 0; mf < 4; ++mf)
#pragma unroll
                for (int nf = 0; nf < 4; ++nf)
                    acc[mf][nf] = __builtin_amdgcn_mfma_f32_16x16x32_bf16(
                        a[mf], b[nf], acc[mf][nf], 0, 0, 0);
        }
    }

    // epilogue: bias + RoPE + bf16 store to qws/kws
    float bv[4];
#pragma unroll
    for (int nf = 0; nf < 4; ++nf) bv[nf] = bias[n0 + wn * 64 + nf * 16 + lr];
    const int h = nt;
    unsigned short* outw = (wn == 0) ? qws : kws;
#pragma unroll
    for (int nf = 0; nf < 4; ++nf) {
        const int d = nf * 16 + lr;          // channel within q or k, 0..63
        const int i = d >> 1;
        const float sgn = (d & 1) ? 1.0f : -1.0f;
#pragma unroll
        for (int mf = 0; mf < 4; ++mf) {
#pragma unroll
            for (int r = 0; r < 4; ++r) {
                const int m = m0 + wm * 64 + mf * 16 + lg * 4 + r;
                const float v = acc[mf][nf][r] + bv[nf];
                const float p = __shfl_xor(v, 1, 64);   // pair partner (col n^1)
                const int s = m & (SEQ - 1), b_ = m >> 10;
                const float2 sc = tab[s * 32 + i];
                const float o = v * sc.y + sgn * p * sc.x;
                outw[(size_t)(((b_ * NHEAD + h) * SEQ + s) * HSZ) + d] = f2bf(o);
            }
        }
    }
}

// GEMM2: logits[bh][m][n] = (Q[bh] . K[bh]^T) / sqrt(12)
// One block per 128x128 output tile; K=64 -> single LDS stage, no K loop.
__global__ __launch_bounds__(256) void qk_logits(
        const unsigned short* __restrict__ qws, const unsigned short* __restrict__ kws,
        float* __restrict__ out) {
    __shared__ unsigned short Qs[128 * 64];
    __shared__ unsigned short Ks[128 * 64];
    const int t  = threadIdx.x;
    const int bh = blockIdx.y;
    const int tm = blockIdx.x >> 3, tn = blockIdx.x & 7;
    const int m0 = tm * 128, n0 = tn * 128;
    const unsigned short* Qb = qws + (size_t)bh * SEQ * HSZ;
    const unsigned short* Kb = kws + (size_t)bh * SEQ * HSZ;
    char* qsb = reinterpret_cast<char*>(Qs);
    char* ksb = reinterpret_cast<char*>(Ks);
    {
        const int c16 = t & 7, r0 = t >> 3;
#pragma unroll
        for (int ii = 0; ii < 4; ++ii) {
            const int r = r0 + ii * 32;
            const uint4 q = *reinterpret_cast<const uint4*>(&Qb[(size_t)(m0 + r) * HSZ + c16 * 8]);
            const uint4 k = *reinterpret_cast<const uint4*>(&Kb[(size_t)(n0 + r) * HSZ + c16 * 8]);
            const int byte = r * 128 + swz16(r, c16) * 16;
            *reinterpret_cast<uint4*>(qsb + byte) = q;
            *reinterpret_cast<uint4*>(ksb + byte) = k;
        }
    }
    __syncthreads();
    const int lane = t & 63, wid = t >> 6;
    const int wm = wid >> 1, wn = wid & 1;
    const int lr = lane & 15, lg = lane >> 4;
    f32x4 acc[4][4] = {};
#pragma unroll
    for (int kk = 0; kk < 2; ++kk) {
        bf16x8 a[4], b[4];
#pragma unroll
        for (int mf = 0; mf < 4; ++mf) {
            const int r = wm * 64 + mf * 16 + lr;
            a[mf] = *reinterpret_cast<const bf16x8*>(qsb + r * 128 + swz16(r, kk * 4 + lg) * 16);
        }
#pragma unroll
        for (int nf = 0; nf < 4; ++nf) {
            const int r = wn * 64 + nf * 16 + lr;
            b[nf] = *reinterpret_cast<const bf16x8*>(ksb + r * 128 + swz16(r, kk * 4 + lg) * 16);
        }
#pragma unroll
        for (int mf = 0; mf < 4; ++mf)
#pragma unroll
            for (int nf = 0; nf < 4; ++nf)
                acc[mf][nf] = __builtin_amdgcn_mfma_f32_16x16x32_bf16(
                    a[mf], b[nf], acc[mf][nf], 0, 0, 0);
    }
    const float scale = 0.28867513459481287f;   // 1/sqrt(12)
    float* ob = out + (size_t)bh * SEQ * SEQ;
#pragma unroll
    for (int mf = 0; mf < 4; ++mf) {
#pragma unroll
        for (int nf = 0; nf < 4; ++nf) {
#pragma unroll
            for (int r = 0; r < 4; ++r) {
                const int m = m0 + wm * 64 + mf * 16 + lg * 4 + r;
                const int n = n0 + wn * 64 + nf * 16 + lr;
                ob[(size_t)m * SEQ + n] = acc[mf][nf][r] * scale;
            }
        }
    }
}

extern "C" void kernel_launch(void* const* d_in, const int* in_sizes, int n_in,
                              void* d_out, int out_size, void* d_ws, size_t ws_size,
                              hipStream_t stream) {
    const float* input = (const float*)d_in[0];
    const float* W     = (const float*)d_in[1];
    const float* bias  = (const float*)d_in[2];
    float* out = (float*)d_out;

    const size_t QK_ELEMS = (size_t)BATCH * NHEAD * SEQ * HSZ;   // 6.29M
    unsigned short* qws = (unsigned short*)d_ws;
    unsigned short* kws = qws + QK_ELEMS;
    unsigned short* Wt  = kws + QK_ELEMS;
    float2* tab = (float2*)(Wt + (size_t)NDIM * KDIM);

    hipLaunchKernelGGL(fill_table, dim3(128), dim3(256), 0, stream, tab);
    hipLaunchKernelGGL(transpose_w, dim3(NDIM / 32, KDIM / 32), dim3(256), 0, stream, W, Wt);
    hipLaunchKernelGGL(gemm1_rope, dim3(NDIM / 128, (BATCH * SEQ) / 128), dim3(256), 0, stream,
                       input, Wt, bias, tab, qws, kws);
    hipLaunchKernelGGL(qk_logits, dim3(64, BATCH * NHEAD), dim3(256), 0, stream, qws, kws, out);
}

// Round 2
// 129.786 us; speedup vs baseline: 1.2305x; 1.2305x over previous
//
#include <hip/hip_runtime.h>
#include <hip/hip_bf16.h>

#define NHEAD 12
#define HSZ   64
#define BATCH 8
#define SEQ   1024
#define KDIM  768
#define NDIM  1536   // NHEAD * HSZ * 2

using f32x4  = __attribute__((ext_vector_type(4))) float;
using bf16x8 = __attribute__((ext_vector_type(8))) __bf16;
typedef unsigned int u32;

__device__ __forceinline__ unsigned short f2bf(float f) {
    unsigned int u = __builtin_bit_cast(unsigned int, f);
    u += 0x7fffu + ((u >> 16) & 1u);   // RNE
    return (unsigned short)(u >> 16);
}

// async global->LDS, 16B per lane; LDS dest = wave-uniform base + lane*16
__device__ __forceinline__ void gl_lds16(const unsigned short* g, unsigned short* l) {
    __builtin_amdgcn_global_load_lds(
        (const __attribute__((address_space(1))) u32*)g,
        (__attribute__((address_space(3))) u32*)l, 16, 0, 0);
}

// byte-block swizzle within a 128B LDS row: 16B block j of row r lives at j^(r&7)
__device__ __forceinline__ int swz16(int row, int c16) { return (c16 ^ (row & 7)); }

// ---------------------------------------------------------------------------
// prep: (a) input fp32 -> bf16   (b) W -> Wt bf16 transpose   (c) sin/cos table
// ---------------------------------------------------------------------------
#define NCONV 3072          // (8192*768)/(256*8)
#define NTRAN 1152          // 48 * 24 tiles of 32x32
#define NTAB  128           // 32768 / 256
__global__ __launch_bounds__(256) void prep(
        const float* __restrict__ input, const float* __restrict__ W,
        unsigned short* __restrict__ Abf, unsigned short* __restrict__ Wt,
        float2* __restrict__ tab) {
    __shared__ unsigned short tl[32][33];
    const int b = blockIdx.x, t = threadIdx.x;
    if (b < NCONV) {
        const size_t base = ((size_t)b * 256 + t) * 8;
        const f32x4 v0 = *reinterpret_cast<const f32x4*>(input + base);
        const f32x4 v1 = *reinterpret_cast<const f32x4*>(input + base + 4);
        uint4 o;
        o.x = (u32)f2bf(v0[0]) | ((u32)f2bf(v0[1]) << 16);
        o.y = (u32)f2bf(v0[2]) | ((u32)f2bf(v0[3]) << 16);
        o.z = (u32)f2bf(v1[0]) | ((u32)f2bf(v1[1]) << 16);
        o.w = (u32)f2bf(v1[2]) | ((u32)f2bf(v1[3]) << 16);
        *reinterpret_cast<uint4*>(Abf + base) = o;
    } else if (b < NCONV + NTRAN) {
        const int tb = b - NCONV;
        const int n0 = (tb % 48) * 32, k0 = (tb / 48) * 32;
        const int tx = t & 31, ty = t >> 5;   // 32 x 8
#pragma unroll
        for (int r = 0; r < 4; ++r)
            tl[ty + r * 8][tx] = f2bf(W[(size_t)(k0 + ty + r * 8) * NDIM + n0 + tx]);
        __syncthreads();
#pragma unroll
        for (int r = 0; r < 4; ++r)
            Wt[(size_t)(n0 + ty + r * 8) * KDIM + k0 + tx] = tl[tx][ty + r * 8];
    } else {
        const int idx = (b - NCONV - NTRAN) * 256 + t;   // < 32768
        const int s = idx >> 5, i = idx & 31;
        const float inv = exp2f(-(float)i * (13.287712379549449f / 32.0f));
        const float ang = (float)s * inv;
        tab[idx] = make_float2(sinf(ang), cosf(ang));
    }
}

// ---------------------------------------------------------------------------
// GEMM1: hidden = input @ W + b, then RoPE, write Q(prescaled)/K bf16 to ws.
// Tile 128x128, BK=64, 4 waves (2x2). N-tile == one head; wn 0->q, 1->k.
// A,B staged via global_load_lds with pre-swizzled source.
// ---------------------------------------------------------------------------
__global__ __launch_bounds__(256) void gemm1_rope(
        const unsigned short* __restrict__ Abf, const unsigned short* __restrict__ Wt,
        const float* __restrict__ bias, const float2* __restrict__ tab,
        unsigned short* __restrict__ qws, unsigned short* __restrict__ kws) {
    __shared__ unsigned short As[128 * 64];   // [m][k] bf16, swizzled 16B blocks
    __shared__ unsigned short Bs[128 * 64];   // [n][k] bf16, swizzled
    const int t  = threadIdx.x;
    const int nt = blockIdx.x, mt = blockIdx.y;
    const int m0 = mt * 128, n0 = nt * 128;
    const int lane = t & 63, wid = t >> 6;
    const int wm = wid >> 1, wn = wid & 1;
    const int lr = lane & 15, lg = lane >> 4;
    // staging lane map: lane l -> row rbase+(l>>3), global 16B-block (l&7)^(l>>3)
    const int lr8 = lane >> 3;
    const int src8 = ((lane & 7) ^ lr8) * 8;   // element offset within 64-elem row

    f32x4 acc[4][4] = {};
    char* asb = reinterpret_cast<char*>(As);
    char* bsb = reinterpret_cast<char*>(Bs);

    for (int kt = 0; kt < KDIM / 64; ++kt) {
        if (kt) __syncthreads();
        const int kbase = kt * 64;
#pragma unroll
        for (int p = 0; p < 4; ++p) {
            const int rb = wid * 32 + p * 8;
            gl_lds16(Abf + (size_t)(m0 + rb + lr8) * KDIM + kbase + src8, As + rb * 64);
            gl_lds16(Wt  + (size_t)(n0 + rb + lr8) * KDIM + kbase + src8, Bs + rb * 64);
        }
        __syncthreads();
#pragma unroll
        for (int kk = 0; kk < 2; ++kk) {
            bf16x8 a[4], b[4];
#pragma unroll
            for (int mf = 0; mf < 4; ++mf) {
                const int r = wm * 64 + mf * 16 + lr;
                a[mf] = *reinterpret_cast<const bf16x8*>(asb + r * 128 + swz16(r, kk * 4 + lg) * 16);
            }
#pragma unroll
            for (int nf = 0; nf < 4; ++nf) {
                const int r = wn * 64 + nf * 16 + lr;
                b[nf] = *reinterpret_cast<const bf16x8*>(bsb + r * 128 + swz16(r, kk * 4 + lg) * 16);
            }
#pragma unroll
            for (int mf = 0; mf < 4; ++mf)
#pragma unroll
                for (int nf = 0; nf < 4; ++nf)
                    acc[mf][nf] = __builtin_amdgcn_mfma_f32_16x16x32_bf16(
                        a[mf], b[nf], acc[mf][nf], 0, 0, 0);
        }
    }

    // epilogue: bias + RoPE (+ 1/sqrt(12) folded into Q) + bf16 store
    float bv[4];
#pragma unroll
    for (int nf = 0; nf < 4; ++nf) bv[nf] = bias[n0 + wn * 64 + nf * 16 + lr];
    const int h = nt;
    unsigned short* outw = (wn == 0) ? qws : kws;
    const float oscale = (wn == 0) ? 0.28867513459481287f : 1.0f;   // 1/sqrt(12)
#pragma unroll
    for (int nf = 0; nf < 4; ++nf) {
        const int d = nf * 16 + lr;          // channel within q or k, 0..63
        const int i = d >> 1;
        const float sgn = (d & 1) ? 1.0f : -1.0f;
#pragma unroll
        for (int mf = 0; mf < 4; ++mf) {
#pragma unroll
            for (int r = 0; r < 4; ++r) {
                const int m = m0 + wm * 64 + mf * 16 + lg * 4 + r;
                const float v = acc[mf][nf][r] + bv[nf];
                const float p = __shfl_xor(v, 1, 64);   // pair partner (col n^1)
                const int s = m & (SEQ - 1), b_ = m >> 10;
                const float2 sc = tab[s * 32 + i];
                const float o = (v * sc.y + sgn * p * sc.x) * oscale;
                outw[(size_t)(((b_ * NHEAD + h) * SEQ + s) * HSZ) + d] = f2bf(o);
            }
        }
    }
}

// ---------------------------------------------------------------------------
// GEMM2: logits[bh][m][n] = Q[bh] . K[bh]^T   (scale pre-folded into Q)
// One block per 128x128 tile; K=64 single stage. XCD-chunked block swizzle.
// ---------------------------------------------------------------------------
__global__ __launch_bounds__(256) void qk_logits(
        const unsigned short* __restrict__ qws, const unsigned short* __restrict__ kws,
        float* __restrict__ out) {
    __shared__ unsigned short Qs[128 * 64];
    __shared__ unsigned short Ks[128 * 64];
    const int t = threadIdx.x;
    // bijective XCD swizzle: 6144 blocks, 768 per XCD -> 12 contiguous bh per XCD
    const int flat = blockIdx.x;
    const int id = (flat & 7) * 768 + (flat >> 3);
    const int bh = id >> 6, tile = id & 63;
    const int tm = tile >> 3, tn = tile & 7;
    const int m0 = tm * 128, n0 = tn * 128;
    const unsigned short* Qb = qws + (size_t)bh * SEQ * HSZ;
    const unsigned short* Kb = kws + (size_t)bh * SEQ * HSZ;
    char* qsb = reinterpret_cast<char*>(Qs);
    char* ksb = reinterpret_cast<char*>(Ks);
    const int lane = t & 63, wid = t >> 6;
    const int lr8 = lane >> 3;
    const int src8 = ((lane & 7) ^ lr8) * 8;
#pragma unroll
    for (int p = 0; p < 4; ++p) {
        const int rb = wid * 32 + p * 8;
        gl_lds16(Qb + (size_t)(m0 + rb + lr8) * HSZ + src8, Qs + rb * 64);
        gl_lds16(Kb + (size_t)(n0 + rb + lr8) * HSZ + src8, Ks + rb * 64);
    }
    __syncthreads();
    const int wm = wid >> 1, wn = wid & 1;
    const int lr = lane & 15, lg = lane >> 4;
    f32x4 acc[4][4] = {};
#pragma unroll
    for (int kk = 0; kk < 2; ++kk) {
        bf16x8 a[4], b[4];
#pragma unroll
        for (int mf = 0; mf < 4; ++mf) {
            const int r = wm * 64 + mf * 16 + lr;
            a[mf] = *reinterpret_cast<const bf16x8*>(qsb + r * 128 + swz16(r, kk * 4 + lg) * 16);
        }
#pragma unroll
        for (int nf = 0; nf < 4; ++nf) {
            const int r = wn * 64 + nf * 16 + lr;
            b[nf] = *reinterpret_cast<const bf16x8*>(ksb + r * 128 + swz16(r, kk * 4 + lg) * 16);
        }
#pragma unroll
        for (int mf = 0; mf < 4; ++mf)
#pragma unroll
            for (int nf = 0; nf < 4; ++nf)
                acc[mf][nf] = __builtin_amdgcn_mfma_f32_16x16x32_bf16(
                    a[mf], b[nf], acc[mf][nf], 0, 0, 0);
    }
    float* ob = out + (size_t)bh * SEQ * SEQ;
#pragma unroll
    for (int mf = 0; mf < 4; ++mf) {
#pragma unroll
        for (int nf = 0; nf < 4; ++nf) {
#pragma unroll
            for (int r = 0; r < 4; ++r) {
                const int m = m0 + wm * 64 + mf * 16 + lg * 4 + r;
                const int n = n0 + wn * 64 + nf * 16 + lr;
                ob[(size_t)m * SEQ + n] = acc[mf][nf][r];
            }
        }
    }
}

extern "C" void kernel_launch(void* const* d_in, const int* in_sizes, int n_in,
                              void* d_out, int out_size, void* d_ws, size_t ws_size,
                              hipStream_t stream) {
    const float* input = (const float*)d_in[0];
    const float* W     = (const float*)d_in[1];
    const float* bias  = (const float*)d_in[2];
    float* out = (float*)d_out;

    const size_t QK_ELEMS = (size_t)BATCH * NHEAD * SEQ * HSZ;   // 6.29M
    unsigned short* qws = (unsigned short*)d_ws;
    unsigned short* kws = qws + QK_ELEMS;
    unsigned short* Wt  = kws + QK_ELEMS;
    unsigned short* Abf = Wt + (size_t)NDIM * KDIM;
    float2* tab = (float2*)(Abf + (size_t)BATCH * SEQ * KDIM);

    hipLaunchKernelGGL(prep, dim3(NCONV + NTRAN + NTAB), dim3(256), 0, stream,
                       input, W, Abf, Wt, tab);
    hipLaunchKernelGGL(gemm1_rope, dim3(NDIM / 128, (BATCH * SEQ) / 128), dim3(256), 0, stream,
                       Abf, Wt, bias, tab, qws, kws);
    hipLaunchKernelGGL(qk_logits, dim3(96 * 64), dim3(256), 0, stream, qws, kws, out);
}